// Round 9
// baseline (194.416 us; speedup 1.0000x reference)
//
#include <hip/hip_runtime.h>
#include <hip/hip_fp16.h>
#include <math.h>

#define NPTS 100000
#define CDIM 64
#define KNN  16

typedef unsigned int uint;
typedef _Float16 f16x8 __attribute__((ext_vector_type(8)));
typedef float    f32x4 __attribute__((ext_vector_type(4)));

// DPP butterfly add: lane gets x + x[lane^mask]; CTRL is an immediate.
template <int CTRL>
__device__ __forceinline__ float dpp_add(float x) {
    int yi = __builtin_amdgcn_mov_dpp(__float_as_int(x), CTRL, 0xF, 0xF, true);
    return x + __int_as_float(yi);
}

// MFMA 16x16x32 f16 fragment maps (symmetric A/B):
//   A[m][k]: m = lane&15, k = quad*8+j      B[k][n]: n = lane&15, k = quad*8+j
//   C/D:     col = lane&15, row = quad*4 + reg
// frag[mat][ct][ks][lane] stores W[k][ct*16 + (lane&15)] over k = ks*32+quad*8+j.
// Used as the A operand it acts as W^T: D[row=outch][col=point].

// ---------------------------------------------------------------------------
// Kernel 0: pre-convert W matrices into fragment order (f16).  8 blocks,
// one fragment per thread (8 strided loads + one 16B store).
// ---------------------------------------------------------------------------
__global__ __launch_bounds__(256) void pack_w(
    const float* __restrict__ Wq, const float* __restrict__ Wk,
    const float* __restrict__ Wv, const float* __restrict__ Wo,
    __half* __restrict__ frag)
{
    const float* Ws[4] = {Wq, Wk, Wv, Wo};
    f16x8* fp = (f16x8*)frag;
    const int e = blockIdx.x * 256 + threadIdx.x;   // 0..2047
    const int lane = e & 63;
    const int ks   = (e >> 6) & 1;
    const int ct   = (e >> 7) & 3;
    const int mat  = e >> 9;
    const int m = lane & 15, quad = lane >> 4;
    const float* W = Ws[mat];
    f16x8 b;
    #pragma unroll
    for (int j = 0; j < 8; ++j)
        b[j] = (_Float16)W[(size_t)(ks * 32 + quad * 8 + j) * 64 + ct * 16 + m];
    fp[e] = b;
}

// feats-side fragment (B operand): B[k][n] = feats[r0 + (lane&15)][quad*8+j].
__device__ __forceinline__ f16x8 load_bfeat(const float* fp, int ks, int quad) {
    const float4 x0 = *(const float4*)(fp + ks * 32 + quad * 8);
    const float4 x1 = *(const float4*)(fp + ks * 32 + quad * 8 + 4);
    f16x8 a;
    a[0] = (_Float16)x0.x; a[1] = (_Float16)x0.y;
    a[2] = (_Float16)x0.z; a[3] = (_Float16)x0.w;
    a[4] = (_Float16)x1.x; a[5] = (_Float16)x1.y;
    a[6] = (_Float16)x1.z; a[7] = (_Float16)x1.w;
    return a;
}

// ---------------------------------------------------------------------------
// Kernel A: q/k/v projection via MFMA, operand-swapped (a=W-frag, b=feats-
// frag) so each lane's C holds 4 consecutive CHANNELS of one point:
// q -> one 8B store, kv -> one 16B store per ct.  One wave per 16-row tile.
// ---------------------------------------------------------------------------
__global__ __launch_bounds__(256) void proj_qkv(
    const float* __restrict__ feats, const __half* __restrict__ frag,
    __half* __restrict__ q, uint* __restrict__ kv)
{
    const int wid = blockIdx.x * 4 + (threadIdx.x >> 6);
    if (wid >= NPTS / 16) return;
    const int lane = threadIdx.x & 63;
    const int m = lane & 15, quad = lane >> 4;

    const f16x8* fp = (const f16x8*)frag;
    f16x8 Wf[3][4][2];
    #pragma unroll
    for (int mat = 0; mat < 3; ++mat)
        #pragma unroll
        for (int ct = 0; ct < 4; ++ct)
            #pragma unroll
            for (int ks = 0; ks < 2; ++ks)
                Wf[mat][ct][ks] = fp[((mat * 4 + ct) * 2 + ks) * 64 + lane];

    const int r0 = wid * 16;
    const float* ap = feats + (size_t)(r0 + m) * 64;
    const f16x8 Bf0 = load_bfeat(ap, 0, quad);
    const f16x8 Bf1 = load_bfeat(ap, 1, quad);

    // This lane's point and channel base.
    const size_t pt = (size_t)(r0 + m);

    #pragma unroll
    for (int ct = 0; ct < 4; ++ct) {
        f32x4 aq = {0.f, 0.f, 0.f, 0.f};
        f32x4 ak = {0.f, 0.f, 0.f, 0.f};
        f32x4 av = {0.f, 0.f, 0.f, 0.f};
        aq = __builtin_amdgcn_mfma_f32_16x16x32_f16(Wf[0][ct][0], Bf0, aq, 0, 0, 0);
        aq = __builtin_amdgcn_mfma_f32_16x16x32_f16(Wf[0][ct][1], Bf1, aq, 0, 0, 0);
        ak = __builtin_amdgcn_mfma_f32_16x16x32_f16(Wf[1][ct][0], Bf0, ak, 0, 0, 0);
        ak = __builtin_amdgcn_mfma_f32_16x16x32_f16(Wf[1][ct][1], Bf1, ak, 0, 0, 0);
        av = __builtin_amdgcn_mfma_f32_16x16x32_f16(Wf[2][ct][0], Bf0, av, 0, 0, 0);
        av = __builtin_amdgcn_mfma_f32_16x16x32_f16(Wf[2][ct][1], Bf1, av, 0, 0, 0);

        const int ch = ct * 16 + quad * 4;            // 4 consecutive channels
        // q: 4 halves = 8B
        uint2 qp;
        qp.x = (uint)__half_as_ushort(__float2half(aq[0]))
             | ((uint)__half_as_ushort(__float2half(aq[1])) << 16);
        qp.y = (uint)__half_as_ushort(__float2half(aq[2]))
             | ((uint)__half_as_ushort(__float2half(aq[3])) << 16);
        *(uint2*)(q + pt * 64 + ch) = qp;
        // kv: 4 dwords = 16B
        uint4 kp;
        kp.x = (uint)__half_as_ushort(__float2half(ak[0]))
             | ((uint)__half_as_ushort(__float2half(av[0])) << 16);
        kp.y = (uint)__half_as_ushort(__float2half(ak[1]))
             | ((uint)__half_as_ushort(__float2half(av[1])) << 16);
        kp.z = (uint)__half_as_ushort(__float2half(ak[2]))
             | ((uint)__half_as_ushort(__float2half(av[2])) << 16);
        kp.w = (uint)__half_as_ushort(__float2half(ak[3]))
             | ((uint)__half_as_ushort(__float2half(av[3])) << 16);
        *(uint4*)(kv + pt * 64 + ch) = kp;
    }
}

// ---------------------------------------------------------------------------
// Kernel B: fused kNN attention + output projection.  Block = 16 points.
// Phase 1: wave w: attention for 4 points (lane=channel, dword kv gather,
// DPP dot, base-2 softmax without max-sub -- scores are O(1) bounded).
// Phase 2: operand-swapped MFMA: a=Wo-frag, b=o-frag from LDS ->
// each lane stores 4 consecutive channels of one point as one float4.
// ---------------------------------------------------------------------------
__global__ __launch_bounds__(256) void attn_out(
    const __half* __restrict__ q, const uint* __restrict__ kv,
    const int* __restrict__ knn, const __half* __restrict__ frag,
    const float* __restrict__ bo, float* __restrict__ out)
{
    __shared__ float sO[16][68];   // +4 pad
    const int t = threadIdx.x;
    const int lane = t & 63;
    const int w = t >> 6;
    const int m = lane & 15, quad = lane >> 4;

    const f16x8* fpb = (const f16x8*)frag;
    const f16x8 Wf0 = fpb[((3 * 4 + w) * 2 + 0) * 64 + lane];
    const f16x8 Wf1 = fpb[((3 * 4 + w) * 2 + 1) * 64 + lane];

    const int n0 = blockIdx.x * 16;
    // scale * log2(e): softmax computed base-2.
    const float SC = 0.3535533905932738f * 1.4426950408889634f;

    #pragma unroll 1
    for (int p = 0; p < 4; ++p) {
        const int n = n0 + w * 4 + p;
        const int ns = __builtin_amdgcn_readfirstlane(n);

        const float qv = __half2float(q[(size_t)n * 64 + lane]);

        const int* kr = knn + (size_t)ns * KNN;
        int idx[KNN];
        #pragma unroll
        for (int i = 0; i < KNN; ++i) idx[i] = kr[i];   // uniform -> s_load

        float sc[KNN], vr[KNN];
        #pragma unroll
        for (int i = 0; i < KNN; ++i) {
            const uint wv = kv[(size_t)idx[i] * 64 + lane];
            const float2 kvf = __half22float2(*(const __half2*)&wv);
            vr[i] = kvf.y;
            float pr = qv * kvf.x;
            pr = dpp_add<0xB1>(pr);    // xor 1
            pr = dpp_add<0x4E>(pr);    // xor 2
            pr = dpp_add<0x141>(pr);   // xor 7 (row_half_mirror)
            sc[i] = __builtin_amdgcn_exp2f(pr * SC);   // |scores| small: no max-sub
        }

        float s = 0.f;
        #pragma unroll
        for (int i = 0; i < KNN; ++i) s += sc[i];
        const float inv = 1.f / s;

        float acc = 0.f;
        #pragma unroll
        for (int i = 0; i < KNN; ++i) acc += sc[i] * vr[i];

        sO[w * 4 + p][lane] = acc * inv;
    }
    __syncthreads();

    // Phase 2 (swapped): b-frag = o[point = m][ch = quad*8+j] from LDS.
    f16x8 Bf0, Bf1;
    {
        const float* ap = &sO[m][0];
        const float4 x0 = *(const float4*)(ap + quad * 8);
        const float4 x1 = *(const float4*)(ap + quad * 8 + 4);
        Bf0[0] = (_Float16)x0.x; Bf0[1] = (_Float16)x0.y;
        Bf0[2] = (_Float16)x0.z; Bf0[3] = (_Float16)x0.w;
        Bf0[4] = (_Float16)x1.x; Bf0[5] = (_Float16)x1.y;
        Bf0[6] = (_Float16)x1.z; Bf0[7] = (_Float16)x1.w;
        const float4 y0 = *(const float4*)(ap + 32 + quad * 8);
        const float4 y1 = *(const float4*)(ap + 32 + quad * 8 + 4);
        Bf1[0] = (_Float16)y0.x; Bf1[1] = (_Float16)y0.y;
        Bf1[2] = (_Float16)y0.z; Bf1[3] = (_Float16)y0.w;
        Bf1[4] = (_Float16)y1.x; Bf1[5] = (_Float16)y1.y;
        Bf1[6] = (_Float16)y1.z; Bf1[7] = (_Float16)y1.w;
    }

    f32x4 ac = {0.f, 0.f, 0.f, 0.f};
    ac = __builtin_amdgcn_mfma_f32_16x16x32_f16(Wf0, Bf0, ac, 0, 0, 0);
    ac = __builtin_amdgcn_mfma_f32_16x16x32_f16(Wf1, Bf1, ac, 0, 0, 0);

    // Lane holds channels w*16+quad*4+{0..3} of point n0+m.
    const int ch = w * 16 + quad * 4;
    const float4 bias = *(const float4*)(bo + ch);
    float4 o;
    o.x = ac[0] + bias.x; o.y = ac[1] + bias.y;
    o.z = ac[2] + bias.z; o.w = ac[3] + bias.w;
    *(float4*)(out + (size_t)(n0 + m) * 64 + ch) = o;
}

extern "C" void kernel_launch(void* const* d_in, const int* in_sizes, int n_in,
                              void* d_out, int out_size, void* d_ws, size_t ws_size,
                              hipStream_t stream) {
    const float* feats = (const float*)d_in[0];
    const int*   knn   = (const int*)d_in[1];
    const float* Wq    = (const float*)d_in[2];
    const float* Wk    = (const float*)d_in[3];
    const float* Wv    = (const float*)d_in[4];
    const float* Wo    = (const float*)d_in[5];
    const float* bo    = (const float*)d_in[6];
    float* out = (float*)d_out;

    __half* frag = (__half*)d_ws;                                  // 32 KB
    __half* q_h  = (__half*)((char*)d_ws + 32768);                 // 12.8 MB
    uint*   kvb  = (uint*)((char*)d_ws + 32768 +
                           (size_t)NPTS * CDIM * sizeof(__half));  // 25.6 MB

    pack_w<<<8, 256, 0, stream>>>(Wq, Wk, Wv, Wo, frag);
    proj_qkv<<<(NPTS / 16 + 3) / 4, 256, 0, stream>>>(feats, frag, q_h, kvb);
    attn_out<<<NPTS / 16, 256, 0, stream>>>(q_h, kvb, knn, frag, bo, out);
}

// Round 10
// 158.593 us; speedup vs baseline: 1.2259x; 1.2259x over previous
//
#include <hip/hip_runtime.h>
#include <hip/hip_fp16.h>
#include <math.h>

#define NPTS 100000
#define CDIM 64
#define KNN  16

typedef unsigned int uint;
typedef _Float16 f16x8 __attribute__((ext_vector_type(8)));
typedef float    f32x4 __attribute__((ext_vector_type(4)));

// DPP butterfly add: lane gets x + x[lane^mask]; CTRL is an immediate.
template <int CTRL>
__device__ __forceinline__ float dpp_add(float x) {
    int yi = __builtin_amdgcn_mov_dpp(__float_as_int(x), CTRL, 0xF, 0xF, true);
    return x + __int_as_float(yi);
}

// MFMA 16x16x32 f16 fragment maps (symmetric A/B):
//   A[m][k]: m = lane&15, k = quad*8+j      B[k][n]: n = lane&15, k = quad*8+j
//   C/D:     col = lane&15, row = quad*4 + reg
// frag[mat][ct][ks][lane] stores W[k][ct*16 + (lane&15)] over k = ks*32+quad*8+j.
// Used as the A operand it acts as W^T: D[row=outch][col=point].

// ---------------------------------------------------------------------------
// Kernel 0: pre-convert W matrices into fragment order (f16).
// ---------------------------------------------------------------------------
__global__ __launch_bounds__(256) void pack_w(
    const float* __restrict__ Wq, const float* __restrict__ Wk,
    const float* __restrict__ Wv, const float* __restrict__ Wo,
    __half* __restrict__ frag)
{
    const float* Ws[4] = {Wq, Wk, Wv, Wo};
    f16x8* fp = (f16x8*)frag;
    const int e = blockIdx.x * 256 + threadIdx.x;   // 0..2047
    const int lane = e & 63;
    const int ks   = (e >> 6) & 1;
    const int ct   = (e >> 7) & 3;
    const int mat  = e >> 9;
    const int m = lane & 15, quad = lane >> 4;
    const float* W = Ws[mat];
    f16x8 b;
    #pragma unroll
    for (int j = 0; j < 8; ++j)
        b[j] = (_Float16)W[(size_t)(ks * 32 + quad * 8 + j) * 64 + ct * 16 + m];
    fp[e] = b;
}

// feats-side fragment (B operand): B[k][n] = feats[r0 + (lane&15)][quad*8+j].
__device__ __forceinline__ f16x8 load_bfeat(const float* fp, int ks, int quad) {
    const float4 x0 = *(const float4*)(fp + ks * 32 + quad * 8);
    const float4 x1 = *(const float4*)(fp + ks * 32 + quad * 8 + 4);
    f16x8 a;
    a[0] = (_Float16)x0.x; a[1] = (_Float16)x0.y;
    a[2] = (_Float16)x0.z; a[3] = (_Float16)x0.w;
    a[4] = (_Float16)x1.x; a[5] = (_Float16)x1.y;
    a[6] = (_Float16)x1.z; a[7] = (_Float16)x1.w;
    return a;
}

// ---------------------------------------------------------------------------
// Kernel A: q/k/v projection via MFMA, operand-swapped (a=W-frag, b=feats-
// frag) so each lane's C holds 4 consecutive CHANNELS of one point:
// q -> one 8B store, kv -> one 16B store per ct.  One wave per 16-row tile.
// ---------------------------------------------------------------------------
__global__ __launch_bounds__(256) void proj_qkv(
    const float* __restrict__ feats, const __half* __restrict__ frag,
    __half* __restrict__ q, uint* __restrict__ kv)
{
    const int wid = blockIdx.x * 4 + (threadIdx.x >> 6);
    if (wid >= NPTS / 16) return;
    const int lane = threadIdx.x & 63;
    const int m = lane & 15, quad = lane >> 4;

    const f16x8* fp = (const f16x8*)frag;
    f16x8 Wf[3][4][2];
    #pragma unroll
    for (int mat = 0; mat < 3; ++mat)
        #pragma unroll
        for (int ct = 0; ct < 4; ++ct)
            #pragma unroll
            for (int ks = 0; ks < 2; ++ks)
                Wf[mat][ct][ks] = fp[((mat * 4 + ct) * 2 + ks) * 64 + lane];

    const int r0 = wid * 16;
    const float* ap = feats + (size_t)(r0 + m) * 64;
    const f16x8 Bf0 = load_bfeat(ap, 0, quad);
    const f16x8 Bf1 = load_bfeat(ap, 1, quad);

    const size_t pt = (size_t)(r0 + m);

    #pragma unroll
    for (int ct = 0; ct < 4; ++ct) {
        f32x4 aq = {0.f, 0.f, 0.f, 0.f};
        f32x4 ak = {0.f, 0.f, 0.f, 0.f};
        f32x4 av = {0.f, 0.f, 0.f, 0.f};
        aq = __builtin_amdgcn_mfma_f32_16x16x32_f16(Wf[0][ct][0], Bf0, aq, 0, 0, 0);
        aq = __builtin_amdgcn_mfma_f32_16x16x32_f16(Wf[0][ct][1], Bf1, aq, 0, 0, 0);
        ak = __builtin_amdgcn_mfma_f32_16x16x32_f16(Wf[1][ct][0], Bf0, ak, 0, 0, 0);
        ak = __builtin_amdgcn_mfma_f32_16x16x32_f16(Wf[1][ct][1], Bf1, ak, 0, 0, 0);
        av = __builtin_amdgcn_mfma_f32_16x16x32_f16(Wf[2][ct][0], Bf0, av, 0, 0, 0);
        av = __builtin_amdgcn_mfma_f32_16x16x32_f16(Wf[2][ct][1], Bf1, av, 0, 0, 0);

        const int ch = ct * 16 + quad * 4;            // 4 consecutive channels
        uint2 qp;
        qp.x = (uint)__half_as_ushort(__float2half(aq[0]))
             | ((uint)__half_as_ushort(__float2half(aq[1])) << 16);
        qp.y = (uint)__half_as_ushort(__float2half(aq[2]))
             | ((uint)__half_as_ushort(__float2half(aq[3])) << 16);
        *(uint2*)(q + pt * 64 + ch) = qp;
        uint4 kp;
        kp.x = (uint)__half_as_ushort(__float2half(ak[0]))
             | ((uint)__half_as_ushort(__float2half(av[0])) << 16);
        kp.y = (uint)__half_as_ushort(__float2half(ak[1]))
             | ((uint)__half_as_ushort(__float2half(av[1])) << 16);
        kp.z = (uint)__half_as_ushort(__float2half(ak[2]))
             | ((uint)__half_as_ushort(__float2half(av[2])) << 16);
        kp.w = (uint)__half_as_ushort(__float2half(ak[3]))
             | ((uint)__half_as_ushort(__float2half(av[3])) << 16);
        *(uint4*)(kv + pt * 64 + ch) = kp;
    }
}

// ---------------------------------------------------------------------------
// Kernel B: fused kNN attention + output projection.  Block = 16 points.
// Phase 1: per point, ALL 16 kv gathers are issued into a register array
// first (16 outstanding loads -> full memory-level parallelism; this is the
// property R9 lost and the reason it regressed), then a separate pass does
// unpack/DPP-dot/exp2.  Base-2 softmax, no max-sub (scores O(1) bounded).
// Phase 2: operand-swapped MFMA (a=Wo-frag, b=o-frag from LDS); each lane
// stores 4 consecutive channels of one point as one float4.
// ---------------------------------------------------------------------------
__global__ __launch_bounds__(256) void attn_out(
    const __half* __restrict__ q, const uint* __restrict__ kv,
    const int* __restrict__ knn, const __half* __restrict__ frag,
    const float* __restrict__ bo, float* __restrict__ out)
{
    __shared__ float sO[16][68];   // +4 pad
    const int t = threadIdx.x;
    const int lane = t & 63;
    const int w = t >> 6;
    const int m = lane & 15, quad = lane >> 4;

    const f16x8* fpb = (const f16x8*)frag;
    const f16x8 Wf0 = fpb[((3 * 4 + w) * 2 + 0) * 64 + lane];
    const f16x8 Wf1 = fpb[((3 * 4 + w) * 2 + 1) * 64 + lane];

    const int n0 = blockIdx.x * 16;
    const float SC = 0.3535533905932738f * 1.4426950408889634f;  // scale*log2e

    #pragma unroll 1
    for (int p = 0; p < 4; ++p) {
        const int n = n0 + w * 4 + p;
        const int ns = __builtin_amdgcn_readfirstlane(n);

        const float qv = __half2float(q[(size_t)n * 64 + lane]);

        const int* kr = knn + (size_t)ns * KNN;
        int idx[KNN];
        #pragma unroll
        for (int i = 0; i < KNN; ++i) idx[i] = kr[i];   // uniform -> s_load

        // Pass 1: issue all gathers (independent, stay outstanding).
        uint u[KNN];
        #pragma unroll
        for (int i = 0; i < KNN; ++i) u[i] = kv[(size_t)idx[i] * 64 + lane];

        // Pass 2: unpack + dot + exp2.
        float sc[KNN], vr[KNN];
        #pragma unroll
        for (int i = 0; i < KNN; ++i) {
            const float2 kvf = __half22float2(*(const __half2*)&u[i]);
            vr[i] = kvf.y;
            float pr = qv * kvf.x;
            pr = dpp_add<0xB1>(pr);    // xor 1
            pr = dpp_add<0x4E>(pr);    // xor 2
            pr = dpp_add<0x141>(pr);   // xor 7 (row_half_mirror)
            sc[i] = __builtin_amdgcn_exp2f(pr * SC);
        }

        float s = 0.f;
        #pragma unroll
        for (int i = 0; i < KNN; ++i) s += sc[i];
        const float inv = 1.f / s;

        float acc = 0.f;
        #pragma unroll
        for (int i = 0; i < KNN; ++i) acc += sc[i] * vr[i];

        sO[w * 4 + p][lane] = acc * inv;
    }
    __syncthreads();

    // Phase 2 (swapped): b-frag = o[point = m][ch = quad*8+j] from LDS.
    f16x8 Bf0, Bf1;
    {
        const float* ap = &sO[m][0];
        const float4 x0 = *(const float4*)(ap + quad * 8);
        const float4 x1 = *(const float4*)(ap + quad * 8 + 4);
        Bf0[0] = (_Float16)x0.x; Bf0[1] = (_Float16)x0.y;
        Bf0[2] = (_Float16)x0.z; Bf0[3] = (_Float16)x0.w;
        Bf0[4] = (_Float16)x1.x; Bf0[5] = (_Float16)x1.y;
        Bf0[6] = (_Float16)x1.z; Bf0[7] = (_Float16)x1.w;
        const float4 y0 = *(const float4*)(ap + 32 + quad * 8);
        const float4 y1 = *(const float4*)(ap + 32 + quad * 8 + 4);
        Bf1[0] = (_Float16)y0.x; Bf1[1] = (_Float16)y0.y;
        Bf1[2] = (_Float16)y0.z; Bf1[3] = (_Float16)y0.w;
        Bf1[4] = (_Float16)y1.x; Bf1[5] = (_Float16)y1.y;
        Bf1[6] = (_Float16)y1.z; Bf1[7] = (_Float16)y1.w;
    }

    f32x4 ac = {0.f, 0.f, 0.f, 0.f};
    ac = __builtin_amdgcn_mfma_f32_16x16x32_f16(Wf0, Bf0, ac, 0, 0, 0);
    ac = __builtin_amdgcn_mfma_f32_16x16x32_f16(Wf1, Bf1, ac, 0, 0, 0);

    const int ch = w * 16 + quad * 4;
    const float4 bias = *(const float4*)(bo + ch);
    float4 o;
    o.x = ac[0] + bias.x; o.y = ac[1] + bias.y;
    o.z = ac[2] + bias.z; o.w = ac[3] + bias.w;
    *(float4*)(out + (size_t)(n0 + m) * 64 + ch) = o;
}

extern "C" void kernel_launch(void* const* d_in, const int* in_sizes, int n_in,
                              void* d_out, int out_size, void* d_ws, size_t ws_size,
                              hipStream_t stream) {
    const float* feats = (const float*)d_in[0];
    const int*   knn   = (const int*)d_in[1];
    const float* Wq    = (const float*)d_in[2];
    const float* Wk    = (const float*)d_in[3];
    const float* Wv    = (const float*)d_in[4];
    const float* Wo    = (const float*)d_in[5];
    const float* bo    = (const float*)d_in[6];
    float* out = (float*)d_out;

    __half* frag = (__half*)d_ws;                                  // 32 KB
    __half* q_h  = (__half*)((char*)d_ws + 32768);                 // 12.8 MB
    uint*   kvb  = (uint*)((char*)d_ws + 32768 +
                           (size_t)NPTS * CDIM * sizeof(__half));  // 25.6 MB

    pack_w<<<8, 256, 0, stream>>>(Wq, Wk, Wv, Wo, frag);
    proj_qkv<<<(NPTS / 16 + 3) / 4, 256, 0, stream>>>(feats, frag, q_h, kvb);
    attn_out<<<NPTS / 16, 256, 0, stream>>>(q_h, kvb, knn, frag, bo, out);
}

// Round 12
// 153.628 us; speedup vs baseline: 1.2655x; 1.0323x over previous
//
#include <hip/hip_runtime.h>
#include <hip/hip_fp16.h>
#include <math.h>

#define NPTS 100000
#define CDIM 64
#define KNN  16

typedef unsigned int uint;
typedef _Float16 f16x8 __attribute__((ext_vector_type(8)));
typedef float    f32x4 __attribute__((ext_vector_type(4)));

// f16 DPP butterfly add: lane gets x + x[lane^mask] (value in low 16 bits).
template <int CTRL>
__device__ __forceinline__ __half dpp_add_h(__half x) {
    int xi = (int)__half_as_ushort(x);
    int yi = __builtin_amdgcn_mov_dpp(xi, CTRL, 0xF, 0xF, true);
    return __hadd(x, __ushort_as_half((unsigned short)yi));
}

// v_cvt_pkrtz_f16_f32: pack two f32 into one dword of two f16 (round-to-zero).
__device__ __forceinline__ uint pkrtz(float a, float b) {
    union { __fp16 __attribute__((ext_vector_type(2))) h; uint u; } cv;
    cv.h = __builtin_amdgcn_cvt_pkrtz(a, b);
    return cv.u;
}

// MFMA 16x16x32 f16 fragment maps (symmetric A/B):
//   A[m][k]: m = lane&15, k = quad*8+j      B[k][n]: n = lane&15, k = quad*8+j
//   C/D:     col = lane&15, row = quad*4 + reg
// frag[mat][ct][ks][lane] stores W[k][ct*16+(lane&15)], k = ks*32+quad*8+j.
// As the A operand it acts as W^T: D[row=outch][col=point].

// ---------------------------------------------------------------------------
// Kernel 0: pre-convert W matrices into fragment order (f16).  Wq is
// pre-scaled by 1/sqrt(8)*log2(e) so attention scores feed exp2 directly.
// ---------------------------------------------------------------------------
__global__ __launch_bounds__(256) void pack_w(
    const float* __restrict__ Wq, const float* __restrict__ Wk,
    const float* __restrict__ Wv, const float* __restrict__ Wo,
    __half* __restrict__ frag)
{
    const float* Ws[4] = {Wq, Wk, Wv, Wo};
    const float scale[4] = {0.3535533905932738f * 1.4426950408889634f, 1.f, 1.f, 1.f};
    f16x8* fp = (f16x8*)frag;
    const int e = blockIdx.x * 256 + threadIdx.x;   // 0..2047
    const int lane = e & 63;
    const int ks   = (e >> 6) & 1;
    const int ct   = (e >> 7) & 3;
    const int mat  = e >> 9;
    const int m = lane & 15, quad = lane >> 4;
    const float* W = Ws[mat];
    const float sc = scale[mat];
    f16x8 b;
    #pragma unroll
    for (int j = 0; j < 8; ++j)
        b[j] = (_Float16)(sc * W[(size_t)(ks * 32 + quad * 8 + j) * 64 + ct * 16 + m]);
    fp[e] = b;
}

// feats-side fragment (B operand): B[k][n] = feats[r0 + (lane&15)][quad*8+j].
__device__ __forceinline__ f16x8 load_bfeat(const float* fp, int ks, int quad) {
    const float4 x0 = *(const float4*)(fp + ks * 32 + quad * 8);
    const float4 x1 = *(const float4*)(fp + ks * 32 + quad * 8 + 4);
    f16x8 a;
    a[0] = (_Float16)x0.x; a[1] = (_Float16)x0.y;
    a[2] = (_Float16)x0.z; a[3] = (_Float16)x0.w;
    a[4] = (_Float16)x1.x; a[5] = (_Float16)x1.y;
    a[6] = (_Float16)x1.z; a[7] = (_Float16)x1.w;
    return a;
}

// ---------------------------------------------------------------------------
// Kernel A: q/k/v projection via MFMA, operand-swapped (a=W-frag, b=feats-
// frag): lane's C holds 4 consecutive CHANNELS of one point.  TWO tiles per
// wave to amortize the 24-fragment load.  Epilogue packs via v_cvt_pkrtz.
// ---------------------------------------------------------------------------
__global__ __launch_bounds__(256) void proj_qkv(
    const float* __restrict__ feats, const __half* __restrict__ frag,
    __half* __restrict__ q, uint* __restrict__ kv)
{
    const int wid = blockIdx.x * 4 + (threadIdx.x >> 6);  // 0..3127
    const int lane = threadIdx.x & 63;
    const int m = lane & 15, quad = lane >> 4;

    const f16x8* fp = (const f16x8*)frag;
    f16x8 Wf[3][4][2];
    #pragma unroll
    for (int mat = 0; mat < 3; ++mat)
        #pragma unroll
        for (int ct = 0; ct < 4; ++ct)
            #pragma unroll
            for (int ks = 0; ks < 2; ++ks)
                Wf[mat][ct][ks] = fp[((mat * 4 + ct) * 2 + ks) * 64 + lane];

    #pragma unroll
    for (int tt = 0; tt < 2; ++tt) {
        const int tile = wid * 2 + tt;
        if (tile >= NPTS / 16) break;
        const int r0 = tile * 16;
        const float* ap = feats + (size_t)(r0 + m) * 64;
        const f16x8 Bf0 = load_bfeat(ap, 0, quad);
        const f16x8 Bf1 = load_bfeat(ap, 1, quad);
        const size_t pt = (size_t)(r0 + m);

        #pragma unroll
        for (int ct = 0; ct < 4; ++ct) {
            f32x4 aq = {0.f, 0.f, 0.f, 0.f};
            f32x4 ak = {0.f, 0.f, 0.f, 0.f};
            f32x4 av = {0.f, 0.f, 0.f, 0.f};
            aq = __builtin_amdgcn_mfma_f32_16x16x32_f16(Wf[0][ct][0], Bf0, aq, 0, 0, 0);
            aq = __builtin_amdgcn_mfma_f32_16x16x32_f16(Wf[0][ct][1], Bf1, aq, 0, 0, 0);
            ak = __builtin_amdgcn_mfma_f32_16x16x32_f16(Wf[1][ct][0], Bf0, ak, 0, 0, 0);
            ak = __builtin_amdgcn_mfma_f32_16x16x32_f16(Wf[1][ct][1], Bf1, ak, 0, 0, 0);
            av = __builtin_amdgcn_mfma_f32_16x16x32_f16(Wf[2][ct][0], Bf0, av, 0, 0, 0);
            av = __builtin_amdgcn_mfma_f32_16x16x32_f16(Wf[2][ct][1], Bf1, av, 0, 0, 0);

            const int ch = ct * 16 + quad * 4;        // 4 consecutive channels
            uint2 qp;
            qp.x = pkrtz(aq[0], aq[1]);
            qp.y = pkrtz(aq[2], aq[3]);
            *(uint2*)(q + pt * 64 + ch) = qp;
            uint4 kp;
            kp.x = pkrtz(ak[0], av[0]);
            kp.y = pkrtz(ak[1], av[1]);
            kp.z = pkrtz(ak[2], av[2]);
            kp.w = pkrtz(ak[3], av[3]);
            *(uint4*)(kv + pt * 64 + ch) = kp;
        }
    }
}

// ---------------------------------------------------------------------------
// Kernel B: fused kNN attention + output projection.  Block = 8 points =
// 4 waves x 2 points; lane = 32*p + l32, lane handles channels 2*l32,2*l32+1.
// Per neighbor: ONE uint2 gather serves a full kv row with 32 lanes (gather
// instrs per point halved).  knn rows are wave-uniform -> 2 s_loads + select.
// Packed-f16 score path (perm split, pk_mul, f16 DPP xor1/xor2), exp2 with
// the scale pre-folded into Wq; V accumulated with pk_fma; o staged as half2
// in LDS.  Phase 2: operand-swapped MFMA over a 16-col tile (8 valid).
// ---------------------------------------------------------------------------
__global__ __launch_bounds__(256) void attn_out(
    const __half* __restrict__ q, const uint* __restrict__ kv,
    const int* __restrict__ knn, const __half* __restrict__ frag,
    const float* __restrict__ bo, float* __restrict__ out)
{
    __shared__ uint sO[8][36];     // o rows as half2 dwords, padded stride 36
    const int t = threadIdx.x;
    const int lane = t & 63;
    const int w = t >> 6;
    const int l32 = lane & 31;
    const int p = lane >> 5;
    const int m = lane & 15, quad = lane >> 4;

    const f16x8* fpb = (const f16x8*)frag;
    const f16x8 Wf0 = fpb[((3 * 4 + w) * 2 + 0) * 64 + lane];
    const f16x8 Wf1 = fpb[((3 * 4 + w) * 2 + 1) * 64 + lane];

    const int n0 = blockIdx.x * 8;
    const int nA = n0 + w * 2;           // wave-uniform
    const int nB = nA + 1;               // wave-uniform
    const int n  = nA + p;

    // knn rows via s_load, per-half-wave select.
    const int* krA = knn + (size_t)nA * KNN;
    const int* krB = knn + (size_t)nB * KNN;
    int idx[KNN];
    #pragma unroll
    for (int i = 0; i < KNN; ++i) idx[i] = p ? krB[i] : krA[i];

    // q: one dword = 2 channels (pre-scaled by 1/sqrt(8)*log2e via Wq).
    const uint qw = ((const uint*)q)[(size_t)n * 32 + l32];
    const __half2 qh = *(const __half2*)&qw;

    // Pass 1: all 16 row-gathers issued first (full MLP).
    uint2 u[KNN];
    #pragma unroll
    for (int i = 0; i < KNN; ++i)
        u[i] = *(const uint2*)(kv + (size_t)idx[i] * 64 + 2 * l32);

    // Pass 2: packed dot + DPP reduce + exp2.
    float sc[KNN];
    __half2 vh[KNN];
    #pragma unroll
    for (int i = 0; i < KNN; ++i) {
        const uint kk = __builtin_amdgcn_perm(u[i].y, u[i].x, 0x05040100u);
        const uint vv = __builtin_amdgcn_perm(u[i].y, u[i].x, 0x07060302u);
        vh[i] = *(const __half2*)&vv;
        const __half2 pr = __hmul2(qh, *(const __half2*)&kk);
        __half s = __hadd(__low2half(pr), __high2half(pr));
        s = dpp_add_h<0xB1>(s);       // xor 1 (within 4-lane head group)
        s = dpp_add_h<0x4E>(s);       // xor 2
        sc[i] = __builtin_amdgcn_exp2f(__half2float(s));
    }

    float ssum = 0.f;
    #pragma unroll
    for (int i = 0; i < KNN; ++i) ssum += sc[i];
    const float inv = __builtin_amdgcn_rcpf(ssum);

    __half2 acc = __float2half2_rn(0.f);
    #pragma unroll
    for (int i = 0; i < KNN; ++i)
        acc = __hfma2(__float2half2_rn(sc[i]), vh[i], acc);
    acc = __hmul2(acc, __float2half2_rn(inv));

    sO[w * 2 + p][l32] = *(const uint*)&acc;
    __syncthreads();

    // Phase 2 (swapped): B-frag = o[point = m&7][ch = quad*8+j] from LDS (f16).
    const uint4 ow = *(const uint4*)&sO[m & 7][quad * 4];
    const f16x8 Bf = *(const f16x8*)&ow;

    f32x4 ac = {0.f, 0.f, 0.f, 0.f};
    ac = __builtin_amdgcn_mfma_f32_16x16x32_f16(Wf0, Bf, ac, 0, 0, 0);
    // Second K-half: channels 32..63 come from dwords 16..31 of the row.
    const uint4 ow2 = *(const uint4*)&sO[m & 7][16 + quad * 4];
    const f16x8 Bf2 = *(const f16x8*)&ow2;
    ac = __builtin_amdgcn_mfma_f32_16x16x32_f16(Wf1, Bf2, ac, 0, 0, 0);

    if (m < 8) {
        const int ch = w * 16 + quad * 4;
        const float4 bias = *(const float4*)(bo + ch);
        float4 o;
        o.x = ac[0] + bias.x; o.y = ac[1] + bias.y;
        o.z = ac[2] + bias.z; o.w = ac[3] + bias.w;
        *(float4*)(out + (size_t)(n0 + m) * 64 + ch) = o;
    }
}

extern "C" void kernel_launch(void* const* d_in, const int* in_sizes, int n_in,
                              void* d_out, int out_size, void* d_ws, size_t ws_size,
                              hipStream_t stream) {
    const float* feats = (const float*)d_in[0];
    const int*   knn   = (const int*)d_in[1];
    const float* Wq    = (const float*)d_in[2];
    const float* Wk    = (const float*)d_in[3];
    const float* Wv    = (const float*)d_in[4];
    const float* Wo    = (const float*)d_in[5];
    const float* bo    = (const float*)d_in[6];
    float* out = (float*)d_out;

    __half* frag = (__half*)d_ws;                                  // 32 KB
    __half* q_h  = (__half*)((char*)d_ws + 32768);                 // 12.8 MB
    uint*   kvb  = (uint*)((char*)d_ws + 32768 +
                           (size_t)NPTS * CDIM * sizeof(__half));  // 25.6 MB

    pack_w<<<8, 256, 0, stream>>>(Wq, Wk, Wv, Wo, frag);
    proj_qkv<<<782, 256, 0, stream>>>(feats, frag, q_h, kvb);      // 2 tiles/wave
    attn_out<<<NPTS / 8, 256, 0, stream>>>(q_h, kvb, knn, frag, bo, out);
}